// Round 3
// baseline (1166.909 us; speedup 1.0000x reference)
//
#include <hip/hip_runtime.h>

// EGKN: E(n) graph kernel network.
#define NN 10000      // nodes
#define NE 300000     // edges
#define DEPTH 4

typedef unsigned int   u32;
typedef unsigned short u16;
typedef unsigned char  u8;

typedef _Float16 half8  __attribute__((ext_vector_type(8)));
typedef _Float16 half2t __attribute__((ext_vector_type(2)));
typedef float  floatx16 __attribute__((ext_vector_type(16)));

__device__ __forceinline__ u32 f2h(float f) {
    f = fminf(fmaxf(f, -60000.f), 60000.f);
    _Float16 h = (_Float16)f;
    return (u32)__builtin_bit_cast(u16, h);
}
__device__ __forceinline__ float h2f(u16 b) {
    return (float)__builtin_bit_cast(_Float16, b);
}
__device__ __forceinline__ u32 pkrtz2(float a, float b) {
    return __builtin_bit_cast(u32, __builtin_amdgcn_cvt_pkrtz(a, b));
}
// u8 pair -> exact fp16 pair via 0x6400 exponent trick: fp16(0x6400|b) = 1024+b
__device__ __forceinline__ u32 dq2(u32 x, u32 sel) {
    const half2t h1024 = {(_Float16)1024.f, (_Float16)1024.f};
    half2t v = __builtin_bit_cast(half2t, __builtin_amdgcn_perm(x, 0x64646464u, sel));
    return __builtin_bit_cast(u32, v - h1024);
}

// ---------------------------------------------------------------------------
__global__ void sentinel_kernel(float* out, int n, float val) {
    int i = blockIdx.x * 256 + threadIdx.x;
    if (i < n) out[i] = val;
}

// ---------------------------------------------------------------------------
__global__ void detect_idx_kernel(const int* __restrict__ ei, int* __restrict__ flag) {
    __shared__ int nz;
    if (threadIdx.x == 0) nz = 0;
    __syncthreads();
    if (ei[threadIdx.x * 2 + 1] != 0) atomicAdd(&nz, 1);
    __syncthreads();
    if (threadIdx.x == 0) *flag = (nz == 0) ? 1 : 0;   // 1 => int64
}

__global__ __launch_bounds__(256) void convert_idx_kernel(
    const int* __restrict__ ei, const int* __restrict__ flag,
    int* __restrict__ ridx, int* __restrict__ cidx)
{
    int e = blockIdx.x * 256 + threadIdx.x;
    if (e >= 2 * NE) return;
    const int is64 = *flag;
    int v = is64 ? ei[2 * e] : ei[e];
    if (e < NE) ridx[e] = v; else cidx[e - NE] = v;
}

// ---------------------------------------------------------------------------
__global__ __launch_bounds__(256) void init_nodes_kernel(
    const float* __restrict__ x, const float* __restrict__ fc1w,
    const float* __restrict__ fc1b, const float* __restrict__ ci,
    float* __restrict__ h, float* __restrict__ coord)
{
    int idx = blockIdx.x * 256 + threadIdx.x;
    if (idx < NN * 32) {
        int v = idx >> 5, f = idx & 31;
        float acc = fc1b[f];
#pragma unroll
        for (int i = 0; i < 3; i++) acc += x[v * 3 + i] * fc1w[i * 32 + f];
        h[idx] = acc;
    }
    if (idx < NN * 3) coord[idx] = ci[idx];
}

// ---------------------------------------------------------------------------
__global__ __launch_bounds__(256) void count_kernel(
    const int* __restrict__ ridx, const int* __restrict__ cidx,
    int* __restrict__ rowcnt, int* __restrict__ colcnt)
{
    int e = blockIdx.x * 256 + threadIdx.x;
    if (e < NE) { atomicAdd(&rowcnt[ridx[e]], 1); atomicAdd(&colcnt[cidx[e]], 1); }
}

__global__ void scan_kernel(const int* __restrict__ colcnt, const int* __restrict__ rowcnt,
                            int* __restrict__ cstart, int* __restrict__ cnext,
                            int* __restrict__ rstart, int* __restrict__ rnext,
                            float* __restrict__ invc, int mode)
{
    __shared__ int partC[256], partR[256];
    const int t = threadIdx.x;
    int sumC = 0, sumR = 0;
    for (int i = 0; i < 40; i++) {
        int v = t * 40 + i;
        if (v < NN) { sumC += colcnt[v]; sumR += rowcnt[v]; }
    }
    partC[t] = sumC; partR[t] = sumR;
    __syncthreads();
    if (t == 0) {
        int rc = 0, rr = 0;
        for (int i = 0; i < 256; i++) {
            int tc = partC[i]; partC[i] = rc; rc += tc;
            int tr = partR[i]; partR[i] = rr; rr += tr;
        }
    }
    __syncthreads();
    int runC = partC[t], runR = partR[t];
    for (int i = 0; i < 40; i++) {
        int v = t * 40 + i;
        if (v < NN) {
            cstart[v] = runC; cnext[v] = runC; runC += colcnt[v];
            if (mode) { rstart[v] = runR; rnext[v] = runR; runR += rowcnt[v]; }
        }
    }
    if (t == 255) { cstart[NN] = runC; if (mode) rstart[NN] = runR; }
    for (int v = t; v < NN; v += 256) invc[v] = 1.0f / fmaxf((float)rowcnt[v], 1.0f);
}

__global__ __launch_bounds__(256) void scatter_kernel(
    const int* __restrict__ cidx, const int* __restrict__ ridx,
    int* __restrict__ cnext, int* __restrict__ rnext,
    int* __restrict__ elist, int* __restrict__ rpos, int* __restrict__ rcol,
    int mode)
{
    int e = blockIdx.x * 256 + threadIdx.x;
    if (e >= NE) return;
    int pos = atomicAdd(&cnext[cidx[e]], 1);
    elist[pos] = e;
    if (mode) {
        int rp = atomicAdd(&rnext[ridx[e]], 1);
        rpos[e] = rp;
        rcol[rp] = cidx[e];
    }
}

// ---------------------------------------------------------------------------
// w2 -> fp16 MFMA B-fragment pack (one-time, 64 KB)
// ---------------------------------------------------------------------------
__global__ __launch_bounds__(256) void w2pack_kernel(
    const float* __restrict__ w2, u16* __restrict__ w2h)
{
    const int slot = blockIdx.x * 256 + threadIdx.x;    // 0..4095
    const int c = slot >> 9, s = (slot >> 6) & 7, l = slot & 63;
    const int li = l & 31, hf = l >> 5;
    const int k0 = s * 16 + hf * 8, col = c * 32 + li;
    u32 pk[8];
#pragma unroll
    for (int j = 0; j < 8; j++) pk[j] = f2h(w2[(size_t)(k0 + j) * 256 + col]);
    uint4 o;
    o.x = pk[0] | (pk[1] << 16);
    o.y = pk[2] | (pk[3] << 16);
    o.z = pk[4] | (pk[5] << 16);
    o.w = pk[6] | (pk[7] << 16);
    *(uint4*)&w2h[(size_t)slot * 8] = o;
}

// cm1 -> fp16 B-fragment pack (2 KB)
__global__ void cm1pack_kernel(const float* __restrict__ cm1w, u16* __restrict__ cmpk)
{
    const int t = threadIdx.x;
    if (t >= 128) return;
    const int s2 = t >> 6, l = t & 63, li = l & 31, hf = l >> 5;
    u32 pk[8];
#pragma unroll
    for (int j = 0; j < 8; j++) pk[j] = f2h(cm1w[(s2 * 16 + hf * 8 + j) * 32 + li]);
    uint4 o;
    o.x = pk[0] | (pk[1] << 16);
    o.y = pk[2] | (pk[3] << 16);
    o.z = pk[4] | (pk[5] << 16);
    o.w = pk[6] | (pk[7] << 16);
    *(uint4*)&cmpk[(size_t)(s2 * 64 + l) * 8] = o;
}

// ---------------------------------------------------------------------------
// w3 -> fp16 MFMA B-fragment pack in Gg storage order (one-time, 512 KB).
// ---------------------------------------------------------------------------
__global__ __launch_bounds__(256) void w3pack_kernel(
    const float* __restrict__ w3, u16* __restrict__ w3g)
{
    const int slot = blockIdx.x * 256 + threadIdx.x;   // 0..32767
    const int lane = slot & 63;
    const int ks   = (slot >> 6) & 1;
    const int pt   = slot >> 7;
    const int p    = pt * 32 + (lane & 31);
    const int kb   = ks * 16 + (lane >> 5) * 8;
    const int s  = p >> 9;
    const int hf = (p >> 8) & 1;
    const int i  = (p >> 3) & 31;
    const int j7 = p & 7;
    const int c  = s * 16 + hf * 8 + j7;
    const float* wp = &w3[(size_t)c * 1024 + i * 32 + kb];
    const float4 x0 = *(const float4*)wp;
    const float4 x1 = *(const float4*)(wp + 4);
    uint4 o;
    o.x = f2h(x0.x) | (f2h(x0.y) << 16);
    o.y = f2h(x0.z) | (f2h(x0.w) << 16);
    o.z = f2h(x1.x) | (f2h(x1.y) << 16);
    o.w = f2h(x1.z) | (f2h(x1.w) << 16);
    *(uint4*)&w3g[(size_t)slot * 8] = o;
}

// ---------------------------------------------------------------------------
// k2 MLP: edge_attr[6] -> 128 -> 256 (relu both). 32 edges/block, u8 out.
// No M_s round trip: per-edge max reduced from the layer-2 accumulators via
// shfl_xor (C-frag rows are edges), quantized bytes staged in u8 LDS.
// LDS 26.1 -> 18.3 KB; launch_bounds(256,6) -> 6 blocks/CU.
// ---------------------------------------------------------------------------
__global__ __launch_bounds__(256, 6) void mlp_k2_kernel(
    const float* __restrict__ ea,
    const float* __restrict__ w1, const float* __restrict__ b1,
    const u16* __restrict__ w2h, const float* __restrict__ b2,
    u8* __restrict__ k2base, u16* __restrict__ k2s)
{
    __shared__ __align__(16) float ea_s[32 * 6];
    __shared__ __align__(16) u16   k1f[4096];          // A-frags: [s][lane][j]
    __shared__ __align__(16) u8    M8[32 * 272];       // quantized [e][c], stride 272
    __shared__ float pmax_s[4][32];
    __shared__ float invS[32];
    const int t  = threadIdx.x;
    const int e0 = blockIdx.x * 32;

    for (int idx = t; idx < 192; idx += 256)
        ea_s[idx] = ea[(size_t)e0 * 6 + idx];
    __syncthreads();

    // layer 1: [32,6]@[6,128] relu -> fp16 fragments
    for (int slot = t; slot < 512; slot += 256) {
        const int s  = slot >> 6;
        const int l  = slot & 63;
        const int li = l & 31, hf = l >> 5;
        const int k0 = s * 16 + hf * 8;
        float acc[8];
        {
            const float4 ba = *(const float4*)&b1[k0];
            const float4 bb = *(const float4*)&b1[k0 + 4];
            acc[0] = ba.x; acc[1] = ba.y; acc[2] = ba.z; acc[3] = ba.w;
            acc[4] = bb.x; acc[5] = bb.y; acc[6] = bb.z; acc[7] = bb.w;
        }
#pragma unroll
        for (int i = 0; i < 6; i++) {
            const float ev = ea_s[li * 6 + i];
            const float4 wa = *(const float4*)&w1[i * 128 + k0];
            const float4 wb = *(const float4*)&w1[i * 128 + k0 + 4];
            acc[0] += ev * wa.x; acc[1] += ev * wa.y;
            acc[2] += ev * wa.z; acc[3] += ev * wa.w;
            acc[4] += ev * wb.x; acc[5] += ev * wb.y;
            acc[6] += ev * wb.z; acc[7] += ev * wb.w;
        }
        uint4 o;
        o.x = pkrtz2(fmaxf(acc[0], 0.f), fmaxf(acc[1], 0.f));
        o.y = pkrtz2(fmaxf(acc[2], 0.f), fmaxf(acc[3], 0.f));
        o.z = pkrtz2(fmaxf(acc[4], 0.f), fmaxf(acc[5], 0.f));
        o.w = pkrtz2(fmaxf(acc[6], 0.f), fmaxf(acc[7], 0.f));
        *(uint4*)&k1f[slot * 8] = o;
    }
    __syncthreads();

    // layer 2: [32,128]@[128,256] via mfma_32x32x16_f16, both col-groups live
    const int w  = t >> 6, l = t & 63;
    const int li = l & 31, hf = l >> 5;
    floatx16 accA, accB;
#pragma unroll
    for (int r = 0; r < 16; r++) { accA[r] = 0.f; accB[r] = 0.f; }
    {
        const int cA = w * 2, cB = w * 2 + 1;
#pragma unroll
        for (int s = 0; s < 8; s++) {
            const half8 a = __builtin_bit_cast(half8,
                *(const uint4*)&k1f[(s * 64 + l) * 8]);
            const half8 bA = __builtin_bit_cast(half8,
                *(const uint4*)&w2h[(((size_t)cA * 8 + s) * 64 + l) * 8]);
            const half8 bB = __builtin_bit_cast(half8,
                *(const uint4*)&w2h[(((size_t)cB * 8 + s) * 64 + l) * 8]);
            accA = __builtin_amdgcn_mfma_f32_32x32x16_f16(a, bA, accA, 0, 0, 0);
            accB = __builtin_amdgcn_mfma_f32_32x32x16_f16(a, bB, accB, 0, 0, 0);
        }
        const float bbA = b2[cA * 32 + li];
        const float bbB = b2[cB * 32 + li];
#pragma unroll
        for (int r = 0; r < 16; r++) {
            accA[r] = fmaxf(accA[r] + bbA, 0.f);
            accB[r] = fmaxf(accB[r] + bbB, 0.f);
        }
    }

    // per-edge max over this wave's 64 cols (rows of C-frag are edges)
#pragma unroll
    for (int r = 0; r < 16; r++) {
        float v = fmaxf(accA[r], accB[r]);
        v = fmaxf(v, __shfl_xor(v, 1, 64));
        v = fmaxf(v, __shfl_xor(v, 2, 64));
        v = fmaxf(v, __shfl_xor(v, 4, 64));
        v = fmaxf(v, __shfl_xor(v, 8, 64));
        v = fmaxf(v, __shfl_xor(v, 16, 64));
        if (li == 0) {
            const int e = (r & 3) + 8 * (r >> 2) + 4 * hf;
            pmax_s[w][e] = v;
        }
    }
    __syncthreads();
    if (t < 32) {
        const float mx = fmaxf(fmaxf(pmax_s[0][t], pmax_s[1][t]),
                               fmaxf(pmax_s[2][t], pmax_s[3][t]));
        k2s[e0 + t] = (u16)f2h(mx / 255.f);
        invS[t] = (mx > 0.f) ? 255.f / mx : 0.f;
    }
    __syncthreads();

    // quantize from registers into u8 LDS (magic-const RNE: byte0 = rint)
    {
        const float magic = 8388608.f;   // 2^23
#pragma unroll
        for (int r = 0; r < 16; r++) {
            const int e = (r & 3) + 8 * (r >> 2) + 4 * hf;
            const float inv = invS[e];
            const u32 qA = __builtin_bit_cast(u32, fmaf(accA[r], inv, magic));
            const u32 qB = __builtin_bit_cast(u32, fmaf(accB[r], inv, magic));
            M8[e * 272 + (w * 2 + 0) * 32 + li] = (u8)qA;
            M8[e * 272 + (w * 2 + 1) * 32 + li] = (u8)qB;
        }
    }
    __syncthreads();

    // copy out: thread t -> edge el=t&31, col-chunk qq=t>>5 (32 cols)
    {
        const int el = t & 31, qq = t >> 5;
        const uint4 o0 = *(const uint4*)&M8[el * 272 + qq * 32];
        const uint4 o1 = *(const uint4*)&M8[el * 272 + qq * 32 + 16];
        u8* outp = k2base + (size_t)(e0 + el) * 256 + qq * 32;
        *(uint4*)outp        = o0;
        *(uint4*)(outp + 16) = o1;
    }
}

// ---------------------------------------------------------------------------
// G = h @ W3t via MFMA. Write-bound: 164 MB fp16 per layer.
// ---------------------------------------------------------------------------
__global__ __launch_bounds__(256) void g_kernel(
    const float* __restrict__ h, const u16* __restrict__ w3g,
    u16* __restrict__ Gg)
{
    const int t = threadIdx.x, w = t >> 6, l = t & 63;
    const int li = l & 31, hf = l >> 5;
    const int n0 = blockIdx.x * 32;
    const int node = n0 + li;

    half8 a0, a1;   // A-frags: row=li(node), k = hf*8+j (+16 for kstep 1)
    if (node < NN) {
        const float* hp = &h[(size_t)node * 32 + hf * 8];
        const float4 x0 = *(const float4*)hp;
        const float4 x1 = *(const float4*)(hp + 4);
        const float4 y0 = *(const float4*)(hp + 16);
        const float4 y1 = *(const float4*)(hp + 20);
        uint4 ua, ub;
        ua.x = pkrtz2(x0.x, x0.y); ua.y = pkrtz2(x0.z, x0.w);
        ua.z = pkrtz2(x1.x, x1.y); ua.w = pkrtz2(x1.z, x1.w);
        ub.x = pkrtz2(y0.x, y0.y); ub.y = pkrtz2(y0.z, y0.w);
        ub.z = pkrtz2(y1.x, y1.y); ub.w = pkrtz2(y1.z, y1.w);
        a0 = __builtin_bit_cast(half8, ua);
        a1 = __builtin_bit_cast(half8, ub);
    } else {
        const uint4 z = make_uint4(0u, 0u, 0u, 0u);
        a0 = __builtin_bit_cast(half8, z);
        a1 = __builtin_bit_cast(half8, z);
    }

    const int pt0 = blockIdx.y * 64 + w * 16;
    const int full = (n0 + 32 <= NN) ? 1 : 0;
#pragma unroll 4
    for (int it = 0; it < 16; it++) {
        const int pt = pt0 + it;
        const uint4 b0u = *(const uint4*)&w3g[((size_t)pt * 2 + 0) * 512 + (size_t)l * 8];
        const uint4 b1u = *(const uint4*)&w3g[((size_t)pt * 2 + 1) * 512 + (size_t)l * 8];
        floatx16 acc;
#pragma unroll
        for (int r = 0; r < 16; r++) acc[r] = 0.f;
        acc = __builtin_amdgcn_mfma_f32_32x32x16_f16(
            a0, __builtin_bit_cast(half8, b0u), acc, 0, 0, 0);
        acc = __builtin_amdgcn_mfma_f32_32x32x16_f16(
            a1, __builtin_bit_cast(half8, b1u), acc, 0, 0, 0);
        if (full) {
#pragma unroll
            for (int r = 0; r < 16; r++) {
                const int nn = n0 + (r & 3) + 8 * (r >> 2) + 4 * hf;
                Gg[(size_t)nn * 8192 + pt * 32 + li] = (u16)f2h(acc[r]);
            }
        } else {
#pragma unroll
            for (int r = 0; r < 16; r++) {
                const int nn = n0 + (r & 3) + 8 * (r >> 2) + 4 * hf;
                if (nn < NN)
                    Gg[(size_t)nn * 8192 + pt * 32 + li] = (u16)f2h(acc[r]);
            }
        }
    }
}

// ---------------------------------------------------------------------------
// MFMA edge pass. One wave64 per col-node n. bvec fused. Staged gr/kr loads
// (2 halves of 8) + shfl-broadcast se/idx -> peak live ~110 VGPR; bounds
// (256,4) = 4 waves/EU for latency hiding of Gg/k2 streams.
// ---------------------------------------------------------------------------
__global__ __launch_bounds__(256, 4) void edge_kernel(
    const int* __restrict__ cstart, const int* __restrict__ elist,
    const int* __restrict__ ridx, const int* __restrict__ rpos,
    const u8* __restrict__ k2base, const u16* __restrict__ k2s,
    const u16* __restrict__ Gg, const float* __restrict__ coord,
    const u16* __restrict__ cmpk, const float* __restrict__ cm1b,
    const float* __restrict__ cm2w, const float* __restrict__ cm2b,
    const float* __restrict__ h, const float* __restrict__ b3,
    float* __restrict__ agg, float* __restrict__ dco,
    u16* __restrict__ mbuf, u16* __restrict__ webuf, int mode)
{
    const int t    = threadIdx.x;
    const int w    = t >> 6;
    const int l    = t & 63;
    const int li   = l & 31;
    const int half = l >> 5;

    __shared__ __align__(16) float Mlds_all[4][32 * 34];
    float* Mlds = Mlds_all[w];

    const int n = blockIdx.x * 4 + w;
    if (n >= NN) return;
    const int s0  = cstart[n];
    const int deg = cstart[n + 1] - s0;
    if (deg == 0) return;

    half8 cmb[2];
    cmb[0] = __builtin_bit_cast(half8, *(const uint4*)&cmpk[(size_t)(0 * 64 + l) * 8]);
    cmb[1] = __builtin_bit_cast(half8, *(const uint4*)&cmpk[(size_t)(1 * 64 + l) * 8]);
    half8 onesb;
#pragma unroll
    for (int j = 0; j < 8; j++) onesb[j] = (_Float16)1.0f;
    const float cm1bq = cm1b[li];
    const float cm2q  = cm2w[li];
    const float cm2b0 = cm2b[0];
    // fused bvec: bv = sum_j b3[li*32+j] * h[n][j]
    float bv = 0.f;
    {
        const float* hn = &h[(size_t)n * 32];
        const float* bp = &b3[(size_t)li * 32];
#pragma unroll
        for (int c2 = 0; c2 < 8; c2++) {
            const float4 hv = *(const float4*)&hn[c2 * 4];
            const float4 bq = *(const float4*)&bp[c2 * 4];
            bv += hv.x * bq.x + hv.y * bq.y + hv.z * bq.z + hv.w * bq.w;
        }
    }
    const float con   = (mode == 0 && li < 3) ? coord[(size_t)n * 3 + li] : 0.f;
    const u16* Gn = Gg + (size_t)n * 8192;

    for (int base = 0; base < deg; base += 32) {
        const int mye   = base + li;
        const int valid = (mye < deg) ? 1 : 0;
        const int eid   = valid ? elist[s0 + mye] : 0;     // lane li <-> edge base+li
        const float se  = valid ? h2f(k2s[eid]) : 0.f;
        const int  idxv = valid ? (mode ? rpos[eid] : ridx[eid]) : 0;

        const u16* grp   = Gn + l * 8;
        const u8*  k2row = k2base + (size_t)eid * 256 + half * 8;

        floatx16 acc;
#pragma unroll
        for (int r = 0; r < 16; r++) acc[r] = 0.f;

        uint4 gr[8]; uint2 kr[8];
#pragma unroll
        for (int s = 0; s < 8; s++) {
            gr[s] = *(const uint4*)(grp + s * 512);
            kr[s] = *(const uint2*)(k2row + s * 16);
        }
#pragma unroll
        for (int s = 0; s < 8; s++) {
            uint4 au;
            au.x = dq2(kr[s].x, 0x00050004u);
            au.y = dq2(kr[s].x, 0x00070006u);
            au.z = dq2(kr[s].y, 0x00050004u);
            au.w = dq2(kr[s].y, 0x00070006u);
            acc = __builtin_amdgcn_mfma_f32_32x32x16_f16(
                __builtin_bit_cast(half8, au),
                __builtin_bit_cast(half8, gr[s]), acc, 0, 0, 0);
        }
#pragma unroll
        for (int s = 0; s < 8; s++) {
            gr[s] = *(const uint4*)(grp + (8 + s) * 512);
            kr[s] = *(const uint2*)(k2row + (8 + s) * 16);
        }
#pragma unroll
        for (int s = 0; s < 8; s++) {
            uint4 au;
            au.x = dq2(kr[s].x, 0x00050004u);
            au.y = dq2(kr[s].x, 0x00070006u);
            au.z = dq2(kr[s].y, 0x00050004u);
            au.w = dq2(kr[s].y, 0x00070006u);
            acc = __builtin_amdgcn_mfma_f32_32x32x16_f16(
                __builtin_bit_cast(half8, au),
                __builtin_bit_cast(half8, gr[s]), acc, 0, 0, 0);
        }

        // per-edge scale commutes with MFMA row-wise: m = se_e * dot + bv
#pragma unroll
        for (int r = 0; r < 16; r++) {
            const int e = (r & 3) + 8 * (r >> 2) + 4 * half;
            acc[r] = acc[r] * __shfl(se, e, 32) + bv;
        }

#pragma unroll
        for (int r = 0; r < 16; r++) {
            const int e = (r & 3) + 8 * (r >> 2) + 4 * half;
            Mlds[e * 34 + li] = acc[r];
        }
        if (mode == 0) {
#pragma unroll
            for (int r = 0; r < 16; r++) {
                const int e = (r & 3) + 8 * (r >> 2) + 4 * half;
                if (base + e < deg)
                    atomicAdd(&agg[(size_t)__shfl(idxv, e, 32) * 32 + li], acc[r]);
            }
        } else {
#pragma unroll
            for (int r = 0; r < 16; r++) {
                const int e = (r & 3) + 8 * (r >> 2) + 4 * half;
                if (base + e < deg)
                    mbuf[(size_t)__shfl(idxv, e, 32) * 32 + li] =
                        __builtin_bit_cast(u16, (_Float16)acc[r]);
            }
        }
        asm volatile("s_waitcnt lgkmcnt(0)" ::: "memory");

        floatx16 acc2;
#pragma unroll
        for (int r = 0; r < 16; r++) acc2[r] = cm1bq;
#pragma unroll
        for (int s2 = 0; s2 < 2; s2++) {
            const float* mp = &Mlds[li * 34 + s2 * 16 + half * 8];
            const float2 m0 = *(const float2*)mp;
            const float2 m1 = *(const float2*)(mp + 2);
            const float2 m2 = *(const float2*)(mp + 4);
            const float2 m3 = *(const float2*)(mp + 6);
            uint4 au;
            au.x = pkrtz2(m0.x, m0.y);
            au.y = pkrtz2(m1.x, m1.y);
            au.z = pkrtz2(m2.x, m2.y);
            au.w = pkrtz2(m3.x, m3.y);
            acc2 = __builtin_amdgcn_mfma_f32_32x32x16_f16(
                __builtin_bit_cast(half8, au), cmb[s2], acc2, 0, 0, 0);
        }

#pragma unroll
        for (int r = 0; r < 16; r++) {
            const int e = (r & 3) + 8 * (r >> 2) + 4 * half;
            Mlds[e * 34 + li] = fmaxf(acc2[r], 0.f) * cm2q;
        }
        asm volatile("s_waitcnt lgkmcnt(0)" ::: "memory");
        floatx16 acc3;
#pragma unroll
        for (int r = 0; r < 16; r++) acc3[r] = cm2b0;
#pragma unroll
        for (int s2 = 0; s2 < 2; s2++) {
            const float* mp = &Mlds[li * 34 + s2 * 16 + half * 8];
            const float2 m0 = *(const float2*)mp;
            const float2 m1 = *(const float2*)(mp + 2);
            const float2 m2 = *(const float2*)(mp + 4);
            const float2 m3 = *(const float2*)(mp + 6);
            uint4 au;
            au.x = pkrtz2(m0.x, m0.y);
            au.y = pkrtz2(m1.x, m1.y);
            au.z = pkrtz2(m2.x, m2.y);
            au.w = pkrtz2(m3.x, m3.y);
            acc3 = __builtin_amdgcn_mfma_f32_32x32x16_f16(
                __builtin_bit_cast(half8, au), onesb, acc3, 0, 0, 0);
        }

        if (mode == 0) {
#pragma unroll
            for (int r = 0; r < 16; r++) {
                const int e = (r & 3) + 8 * (r >> 2) + 4 * half;
                if (base + e < deg && li < 3) {
                    const int rr = __shfl(idxv, e, 32);
                    const float d = coord[(size_t)rr * 3 + li] - con;
                    atomicAdd(&dco[(size_t)rr * 3 + li], d * acc3[r]);
                }
            }
        } else {
#pragma unroll
            for (int r = 0; r < 16; r++) {
                const int e = (r & 3) + 8 * (r >> 2) + 4 * half;
                const int ie = __shfl(idxv, e, 32);
                if (base + e < deg && li == 0)
                    webuf[ie] = __builtin_bit_cast(u16, (_Float16)acc3[r]);
            }
        }
    }
}

// ---------------------------------------------------------------------------
__global__ __launch_bounds__(256) void node_update_kernel(
    float* __restrict__ h, float* __restrict__ agg,
    float* __restrict__ coord, float* __restrict__ dco,
    const float* __restrict__ invc)
{
    int idx = blockIdx.x * 256 + threadIdx.x;
    if (idx < NN * 32) {
        int v = idx >> 5;
        h[idx] = fmaxf(h[idx] + agg[idx] * invc[v], 0.f);
        agg[idx] = 0.f;
    }
    if (idx < NN * 3) {
        coord[idx] += dco[idx] * invc[idx / 3];
        dco[idx] = 0.f;
    }
}

// ---------------------------------------------------------------------------
__global__ __launch_bounds__(256) void node_update2_kernel(
    float* __restrict__ h, const float* __restrict__ coordCur,
    float* __restrict__ coordNew, const u16* __restrict__ mbuf,
    const u16* __restrict__ webuf, const int* __restrict__ rcol,
    const int* __restrict__ rstart, const float* __restrict__ invc)
{
    const int t = threadIdx.x, w = t >> 6, l = t & 63;
    const int li = l & 31, half = l >> 5;
    const int v = blockIdx.x * 4 + w;
    if (v >= NN) return;
    const int s0 = rstart[v], s1 = rstart[v + 1];
    const float iv = invc[v];

    float acc = 0.f;
    for (int s = s0 + half; s < s1; s += 2)
        acc += h2f(mbuf[(size_t)s * 32 + li]);
    acc += __shfl_xor(acc, 32, 64);
    if (half == 0)
        h[(size_t)v * 32 + li] = fmaxf(h[(size_t)v * 32 + li] + acc * iv, 0.f);

    const float c0 = coordCur[(size_t)v * 3 + 0];
    const float c1 = coordCur[(size_t)v * 3 + 1];
    const float c2 = coordCur[(size_t)v * 3 + 2];
    float p0 = 0.f, p1 = 0.f, p2 = 0.f;
    for (int s = s0 + l; s < s1; s += 64) {
        const float we = h2f(webuf[s]);
        const int col = rcol[s];
        p0 += (c0 - coordCur[(size_t)col * 3 + 0]) * we;
        p1 += (c1 - coordCur[(size_t)col * 3 + 1]) * we;
        p2 += (c2 - coordCur[(size_t)col * 3 + 2]) * we;
    }
#pragma unroll
    for (int off = 32; off >= 1; off >>= 1) {
        p0 += __shfl_xor(p0, off, 64);
        p1 += __shfl_xor(p1, off, 64);
        p2 += __shfl_xor(p2, off, 64);
    }
    if (l == 0) {
        coordNew[(size_t)v * 3 + 0] = c0 + p0 * iv;
        coordNew[(size_t)v * 3 + 1] = c1 + p1 * iv;
        coordNew[(size_t)v * 3 + 2] = c2 + p2 * iv;
    }
}

// ---------------------------------------------------------------------------
__global__ __launch_bounds__(256) void final_kernel(
    const float* __restrict__ h, const float* __restrict__ coord,
    const float* __restrict__ wa, const float* __restrict__ ba,
    const float* __restrict__ wb, const float* __restrict__ bb,
    float* __restrict__ out)
{
    const int lane = threadIdx.x & 63;
    const int v = blockIdx.x * 4 + (threadIdx.x >> 6);
    if (v >= NN) return;
    const float hreg = (lane < 32) ? h[(size_t)v * 32 + lane] : 0.f;
    float acc = ba[lane];
#pragma unroll
    for (int f = 0; f < 32; f++) acc += __shfl(hreg, f, 64) * wa[f * 64 + lane];
    float part = fmaxf(acc, 0.f) * wb[lane];
#pragma unroll
    for (int off = 32; off >= 1; off >>= 1) part += __shfl_xor(part, off, 64);
    if (lane == 0) out[v] = part + bb[0];
    if (lane < 3) out[NN + (size_t)v * 3 + lane] = coord[(size_t)v * 3 + lane];
}

// ---------------------------------------------------------------------------
extern "C" void kernel_launch(void* const* d_in, const int* in_sizes, int n_in,
                              void* d_out, int out_size, void* d_ws, size_t ws_size,
                              hipStream_t stream)
{
    const float* x    = (const float*)d_in[0];
    const int*   ei   = (const int*)d_in[1];
    const float* ea   = (const float*)d_in[2];
    const float* ci   = (const float*)d_in[3];
    const float* fc1w = (const float*)d_in[4];
    const float* fc1b = (const float*)d_in[5];
    const float* k1w  = (const float*)d_in[6];
    const float* k1b  = (const float*)d_in[7];
    const float* k2w  = (const float*)d_in[8];
    const float* k2b  = (const float*)d_in[9];
    const float* k3w  = (const float*)d_in[10];
    const float* k3b  = (const float*)d_in[11];
    const float* cm1w = (const float*)d_in[12];
    const float* cm1b = (const float*)d_in[13];
    const float* cm2w = (const float*)d_in[14];
    const float* cm2b = (const float*)d_in[15];
    const float* f2aw = (const float*)d_in[16];
    const float* f2ab = (const float*)d_in[17];
    const float* f2bw = (const float*)d_in[18];
    const float* f2bb = (const float*)d_in[19];

    size_t o_k2, o_k2s, o_G, o_h, o_coA, o_coB, o_invc, o_rc, o_cc,
           o_cs, o_rs, o_cn, o_rn, o_el, o_w2h, o_cmpk, o_w3g, o_agg, o_dco,
           o_ri, o_ci, o_rp, o_rcl, o_mb, o_wb;
#define ALGN(v) (((v) + 255) & ~(size_t)255)
    auto carve = [&](int mode) -> size_t {
        size_t o = 0;
        o_k2  = o; o += ALGN((size_t)NE * 256);
        o_k2s = o; o += ALGN((size_t)NE * 2);          // fp16
        o_G   = o; o += ALGN((size_t)NN * 8192 * 2);
        o_h   = o; o += ALGN((size_t)NN * 32 * 4);
        o_coA = o; o += ALGN((size_t)NN * 3 * 4);
        o_invc= o; o += ALGN((size_t)NN * 4);
        o_rc  = o; o += ALGN((size_t)NN * 4);
        o_cc  = o; o += ALGN((size_t)NN * 4);
        o_cs  = o; o += ALGN((size_t)(NN + 1) * 4);
        o_cn  = o; o += ALGN((size_t)NN * 4);
        o_el  = o; o += ALGN((size_t)NE * 4);
        o_w2h = o; o += ALGN((size_t)128 * 256 * 2);
        o_cmpk= o; o += ALGN((size_t)1024 * 2);
        o_w3g = o; o += ALGN((size_t)32768 * 8 * 2);   // 512 KB W3 B-frag pack
        if (mode == 0) {
            o_agg = o; o += ALGN((size_t)NN * 32 * 4);
            o_dco = o; o += ALGN((size_t)NN * 3 * 4);
            o_ri  = o; o += ALGN((size_t)NE * 4);
            o_ci  = o; o += ALGN((size_t)NE * 4);
            o_coB = o_coA; o_rs = o_cs; o_rn = o_cn;
            o_rp = o_el; o_rcl = o_el; o_mb = o_k2; o_wb = o_k2;
        } else {
            o_coB = o; o += ALGN((size_t)NN * 3 * 4);
            o_rs  = o; o += ALGN((size_t)(NN + 1) * 4);
            o_rn  = o; o += ALGN((size_t)NN * 4);
            o_rp  = o; o += ALGN((size_t)NE * 4);
            o_rcl = o; o += ALGN((size_t)NE * 4);
            const size_t u = o;
            o_ri = u; o_ci = u + ALGN((size_t)NE * 4);
            o_mb = u; o_wb = u + ALGN((size_t)NE * 32 * 2);
            const size_t setup_sz = 2 * ALGN((size_t)NE * 4);
            const size_t layer_sz = ALGN((size_t)NE * 32 * 2) + ALGN((size_t)NE * 2);
            o += (setup_sz > layer_sz) ? setup_sz : layer_sz;
            o_agg = o_k2; o_dco = o_k2;
        }
        return o;
    };
    int mode = (ws_size >= carve(1)) ? 1 : 0;
    size_t need = carve(mode);
    if (ws_size < need) {
        sentinel_kernel<<<(NN * 4 + 255) / 256, 256, 0, stream>>>((float*)d_out, NN * 4, 1.0e6f);
        return;
    }

    char* wsb = (char*)d_ws;
    u8*    k2g   = (u8*)(wsb + o_k2);
    u16*   k2s   = (u16*)(wsb + o_k2s);
    u16*   Gg    = (u16*)(wsb + o_G);
    float* h     = (float*)(wsb + o_h);
    float* coA   = (float*)(wsb + o_coA);
    float* coB   = (float*)(wsb + o_coB);
    float* invc  = (float*)(wsb + o_invc);
    int*   rowcnt= (int*)(wsb + o_rc);
    int*   colcnt= (int*)(wsb + o_cc);
    int*   cstart= (int*)(wsb + o_cs);
    int*   rstart= (int*)(wsb + o_rs);
    int*   cnext = (int*)(wsb + o_cn);
    int*   rnext = (int*)(wsb + o_rn);
    int*   elist = (int*)(wsb + o_el);
    u16*   w2h   = (u16*)(wsb + o_w2h);
    u16*   cmpk  = (u16*)(wsb + o_cmpk);
    u16*   w3g   = (u16*)(wsb + o_w3g);
    float* agg   = (float*)(wsb + o_agg);
    float* dco   = (float*)(wsb + o_dco);
    int*   ridx  = (int*)(wsb + o_ri);
    int*   cidx  = (int*)(wsb + o_ci);
    int*   rpos  = (int*)(wsb + o_rp);
    int*   rcol  = (int*)(wsb + o_rcl);
    u16*   mbuf  = (u16*)(wsb + o_mb);
    u16*   webuf = (u16*)(wsb + o_wb);

    hipMemsetAsync(rowcnt, 0, (size_t)NN * 4, stream);
    hipMemsetAsync(colcnt, 0, (size_t)NN * 4, stream);
    if (mode == 0) {
        hipMemsetAsync(agg, 0, (size_t)NN * 32 * 4, stream);
        hipMemsetAsync(dco, 0, (size_t)NN * 3 * 4, stream);
    }

    detect_idx_kernel<<<1, 256, 0, stream>>>(ei, cnext);
    convert_idx_kernel<<<(2 * NE + 255) / 256, 256, 0, stream>>>(ei, cnext, ridx, cidx);
    init_nodes_kernel<<<(NN * 32 + 255) / 256, 256, 0, stream>>>(x, fc1w, fc1b, ci, h, coA);
    count_kernel<<<(NE + 255) / 256, 256, 0, stream>>>(ridx, cidx, rowcnt, colcnt);
    scan_kernel<<<1, 256, 0, stream>>>(colcnt, rowcnt, cstart, cnext, rstart, rnext,
                                       invc, mode);
    scatter_kernel<<<(NE + 255) / 256, 256, 0, stream>>>(cidx, ridx, cnext, rnext,
                                                         elist, rpos, rcol, mode);
    w2pack_kernel<<<16, 256, 0, stream>>>(k2w, w2h);
    cm1pack_kernel<<<1, 128, 0, stream>>>(cm1w, cmpk);
    w3pack_kernel<<<128, 256, 0, stream>>>(k3w, w3g);
    mlp_k2_kernel<<<NE / 32, 256, 0, stream>>>(ea, k1w, k1b, w2h, k2b, k2g, k2s);

    float* coCur = coA;
    float* coAlt = coB;
    const dim3 ggrid((NN + 31) / 32, 4);
    for (int l = 0; l < DEPTH; l++) {
        g_kernel<<<ggrid, 256, 0, stream>>>(h, w3g, Gg);
        edge_kernel<<<(NN + 3) / 4, 256, 0, stream>>>(cstart, elist, ridx, rpos,
                                                      k2g, k2s, Gg, coCur, cmpk,
                                                      cm1b, cm2w, cm2b, h, k3b,
                                                      agg, dco, mbuf, webuf, mode);
        if (mode == 1) {
            node_update2_kernel<<<(NN + 3) / 4, 256, 0, stream>>>(
                h, coCur, coAlt, mbuf, webuf, rcol, rstart, invc);
            float* tmp = coCur; coCur = coAlt; coAlt = tmp;
        } else {
            node_update_kernel<<<(NN * 32 + 255) / 256, 256, 0, stream>>>(
                h, agg, coCur, dco, invc);
        }
    }
    final_kernel<<<(NN + 3) / 4, 256, 0, stream>>>(h, coCur, f2aw, f2ab, f2bw, f2bb,
                                                   (float*)d_out);
}

// Round 4
// 775.530 us; speedup vs baseline: 1.5047x; 1.5047x over previous
//
#include <hip/hip_runtime.h>

// EGKN: E(n) graph kernel network.
#define NN 10000      // nodes
#define NE 300000     // edges
#define DEPTH 4

typedef unsigned int   u32;
typedef unsigned short u16;
typedef unsigned char  u8;

typedef _Float16 half8  __attribute__((ext_vector_type(8)));
typedef _Float16 half2t __attribute__((ext_vector_type(2)));
typedef float  floatx16 __attribute__((ext_vector_type(16)));

__device__ __forceinline__ u32 f2h(float f) {
    f = fminf(fmaxf(f, -60000.f), 60000.f);
    _Float16 h = (_Float16)f;
    return (u32)__builtin_bit_cast(u16, h);
}
__device__ __forceinline__ float h2f(u16 b) {
    return (float)__builtin_bit_cast(_Float16, b);
}
__device__ __forceinline__ u32 pkrtz2(float a, float b) {
    return __builtin_bit_cast(u32, __builtin_amdgcn_cvt_pkrtz(a, b));
}
// u8 pair -> exact fp16 pair via 0x6400 exponent trick: fp16(0x6400|b) = 1024+b
__device__ __forceinline__ u32 dq2(u32 x, u32 sel) {
    const half2t h1024 = {(_Float16)1024.f, (_Float16)1024.f};
    half2t v = __builtin_bit_cast(half2t, __builtin_amdgcn_perm(x, 0x64646464u, sel));
    return __builtin_bit_cast(u32, v - h1024);
}

// ---------------------------------------------------------------------------
__global__ void sentinel_kernel(float* out, int n, float val) {
    int i = blockIdx.x * 256 + threadIdx.x;
    if (i < n) out[i] = val;
}

// ---------------------------------------------------------------------------
__global__ void detect_idx_kernel(const int* __restrict__ ei, int* __restrict__ flag) {
    __shared__ int nz;
    if (threadIdx.x == 0) nz = 0;
    __syncthreads();
    if (ei[threadIdx.x * 2 + 1] != 0) atomicAdd(&nz, 1);
    __syncthreads();
    if (threadIdx.x == 0) *flag = (nz == 0) ? 1 : 0;   // 1 => int64
}

__global__ __launch_bounds__(256) void convert_idx_kernel(
    const int* __restrict__ ei, const int* __restrict__ flag,
    int* __restrict__ ridx, int* __restrict__ cidx)
{
    int e = blockIdx.x * 256 + threadIdx.x;
    if (e >= 2 * NE) return;
    const int is64 = *flag;
    int v = is64 ? ei[2 * e] : ei[e];
    if (e < NE) ridx[e] = v; else cidx[e - NE] = v;
}

// ---------------------------------------------------------------------------
__global__ __launch_bounds__(256) void init_nodes_kernel(
    const float* __restrict__ x, const float* __restrict__ fc1w,
    const float* __restrict__ fc1b, const float* __restrict__ ci,
    float* __restrict__ h, float* __restrict__ coord)
{
    int idx = blockIdx.x * 256 + threadIdx.x;
    if (idx < NN * 32) {
        int v = idx >> 5, f = idx & 31;
        float acc = fc1b[f];
#pragma unroll
        for (int i = 0; i < 3; i++) acc += x[v * 3 + i] * fc1w[i * 32 + f];
        h[idx] = acc;
    }
    if (idx < NN * 3) coord[idx] = ci[idx];
}

// ---------------------------------------------------------------------------
__global__ __launch_bounds__(256) void count_kernel(
    const int* __restrict__ ridx, const int* __restrict__ cidx,
    int* __restrict__ rowcnt, int* __restrict__ colcnt)
{
    int e = blockIdx.x * 256 + threadIdx.x;
    if (e < NE) { atomicAdd(&rowcnt[ridx[e]], 1); atomicAdd(&colcnt[cidx[e]], 1); }
}

__global__ void scan_kernel(const int* __restrict__ colcnt, const int* __restrict__ rowcnt,
                            int* __restrict__ cstart, int* __restrict__ cnext,
                            int* __restrict__ rstart, int* __restrict__ rnext,
                            float* __restrict__ invc, int mode)
{
    __shared__ int partC[256], partR[256];
    const int t = threadIdx.x;
    int sumC = 0, sumR = 0;
    for (int i = 0; i < 40; i++) {
        int v = t * 40 + i;
        if (v < NN) { sumC += colcnt[v]; sumR += rowcnt[v]; }
    }
    partC[t] = sumC; partR[t] = sumR;
    __syncthreads();
    if (t == 0) {
        int rc = 0, rr = 0;
        for (int i = 0; i < 256; i++) {
            int tc = partC[i]; partC[i] = rc; rc += tc;
            int tr = partR[i]; partR[i] = rr; rr += tr;
        }
    }
    __syncthreads();
    int runC = partC[t], runR = partR[t];
    for (int i = 0; i < 40; i++) {
        int v = t * 40 + i;
        if (v < NN) {
            cstart[v] = runC; cnext[v] = runC; runC += colcnt[v];
            if (mode) { rstart[v] = runR; rnext[v] = runR; runR += rowcnt[v]; }
        }
    }
    if (t == 255) { cstart[NN] = runC; if (mode) rstart[NN] = runR; }
    for (int v = t; v < NN; v += 256) invc[v] = 1.0f / fmaxf((float)rowcnt[v], 1.0f);
}

__global__ __launch_bounds__(256) void scatter_kernel(
    const int* __restrict__ cidx, const int* __restrict__ ridx,
    int* __restrict__ cnext, int* __restrict__ rnext,
    int* __restrict__ elist, int* __restrict__ rpos, int* __restrict__ rcol,
    int mode)
{
    int e = blockIdx.x * 256 + threadIdx.x;
    if (e >= NE) return;
    int pos = atomicAdd(&cnext[cidx[e]], 1);
    elist[pos] = e;
    if (mode) {
        int rp = atomicAdd(&rnext[ridx[e]], 1);
        rpos[e] = rp;
        rcol[rp] = cidx[e];
    }
}

// ---------------------------------------------------------------------------
// w2 -> fp16 MFMA B-fragment pack (one-time, 64 KB)
// ---------------------------------------------------------------------------
__global__ __launch_bounds__(256) void w2pack_kernel(
    const float* __restrict__ w2, u16* __restrict__ w2h)
{
    const int slot = blockIdx.x * 256 + threadIdx.x;    // 0..4095
    const int c = slot >> 9, s = (slot >> 6) & 7, l = slot & 63;
    const int li = l & 31, hf = l >> 5;
    const int k0 = s * 16 + hf * 8, col = c * 32 + li;
    u32 pk[8];
#pragma unroll
    for (int j = 0; j < 8; j++) pk[j] = f2h(w2[(size_t)(k0 + j) * 256 + col]);
    uint4 o;
    o.x = pk[0] | (pk[1] << 16);
    o.y = pk[2] | (pk[3] << 16);
    o.z = pk[4] | (pk[5] << 16);
    o.w = pk[6] | (pk[7] << 16);
    *(uint4*)&w2h[(size_t)slot * 8] = o;
}

// cm1 -> fp16 B-fragment pack (2 KB)
__global__ void cm1pack_kernel(const float* __restrict__ cm1w, u16* __restrict__ cmpk)
{
    const int t = threadIdx.x;
    if (t >= 128) return;
    const int s2 = t >> 6, l = t & 63, li = l & 31, hf = l >> 5;
    u32 pk[8];
#pragma unroll
    for (int j = 0; j < 8; j++) pk[j] = f2h(cm1w[(s2 * 16 + hf * 8 + j) * 32 + li]);
    uint4 o;
    o.x = pk[0] | (pk[1] << 16);
    o.y = pk[2] | (pk[3] << 16);
    o.z = pk[4] | (pk[5] << 16);
    o.w = pk[6] | (pk[7] << 16);
    *(uint4*)&cmpk[(size_t)(s2 * 64 + l) * 8] = o;
}

// ---------------------------------------------------------------------------
// w3 -> fp16 MFMA B-fragment pack in Gg storage order (one-time, 512 KB).
// ---------------------------------------------------------------------------
__global__ __launch_bounds__(256) void w3pack_kernel(
    const float* __restrict__ w3, u16* __restrict__ w3g)
{
    const int slot = blockIdx.x * 256 + threadIdx.x;   // 0..32767
    const int lane = slot & 63;
    const int ks   = (slot >> 6) & 1;
    const int pt   = slot >> 7;
    const int p    = pt * 32 + (lane & 31);
    const int kb   = ks * 16 + (lane >> 5) * 8;
    const int s  = p >> 9;
    const int hf = (p >> 8) & 1;
    const int i  = (p >> 3) & 31;
    const int j7 = p & 7;
    const int c  = s * 16 + hf * 8 + j7;
    const float* wp = &w3[(size_t)c * 1024 + i * 32 + kb];
    const float4 x0 = *(const float4*)wp;
    const float4 x1 = *(const float4*)(wp + 4);
    uint4 o;
    o.x = f2h(x0.x) | (f2h(x0.y) << 16);
    o.y = f2h(x0.z) | (f2h(x0.w) << 16);
    o.z = f2h(x1.x) | (f2h(x1.y) << 16);
    o.w = f2h(x1.z) | (f2h(x1.w) << 16);
    *(uint4*)&w3g[(size_t)slot * 8] = o;
}

// ---------------------------------------------------------------------------
// k2 MLP: edge_attr[6] -> 128 -> 256 (relu both). 32 edges/block, u8 out.
// Register-resident epilogue (no fp16 LDS round-trip); LDS 18.3 KB.
// ---------------------------------------------------------------------------
__global__ __launch_bounds__(256, 6) void mlp_k2_kernel(
    const float* __restrict__ ea,
    const float* __restrict__ w1, const float* __restrict__ b1,
    const u16* __restrict__ w2h, const float* __restrict__ b2,
    u8* __restrict__ k2base, u16* __restrict__ k2s)
{
    __shared__ __align__(16) float ea_s[32 * 6];
    __shared__ __align__(16) u16   k1f[4096];          // A-frags: [s][lane][j]
    __shared__ __align__(16) u8    M8[32 * 272];       // quantized [e][c], stride 272
    __shared__ float pmax_s[4][32];
    __shared__ float invS[32];
    const int t  = threadIdx.x;
    const int e0 = blockIdx.x * 32;

    for (int idx = t; idx < 192; idx += 256)
        ea_s[idx] = ea[(size_t)e0 * 6 + idx];
    __syncthreads();

    // layer 1: [32,6]@[6,128] relu -> fp16 fragments
    for (int slot = t; slot < 512; slot += 256) {
        const int s  = slot >> 6;
        const int l  = slot & 63;
        const int li = l & 31, hf = l >> 5;
        const int k0 = s * 16 + hf * 8;
        float acc[8];
        {
            const float4 ba = *(const float4*)&b1[k0];
            const float4 bb = *(const float4*)&b1[k0 + 4];
            acc[0] = ba.x; acc[1] = ba.y; acc[2] = ba.z; acc[3] = ba.w;
            acc[4] = bb.x; acc[5] = bb.y; acc[6] = bb.z; acc[7] = bb.w;
        }
#pragma unroll
        for (int i = 0; i < 6; i++) {
            const float ev = ea_s[li * 6 + i];
            const float4 wa = *(const float4*)&w1[i * 128 + k0];
            const float4 wb = *(const float4*)&w1[i * 128 + k0 + 4];
            acc[0] += ev * wa.x; acc[1] += ev * wa.y;
            acc[2] += ev * wa.z; acc[3] += ev * wa.w;
            acc[4] += ev * wb.x; acc[5] += ev * wb.y;
            acc[6] += ev * wb.z; acc[7] += ev * wb.w;
        }
        uint4 o;
        o.x = pkrtz2(fmaxf(acc[0], 0.f), fmaxf(acc[1], 0.f));
        o.y = pkrtz2(fmaxf(acc[2], 0.f), fmaxf(acc[3], 0.f));
        o.z = pkrtz2(fmaxf(acc[4], 0.f), fmaxf(acc[5], 0.f));
        o.w = pkrtz2(fmaxf(acc[6], 0.f), fmaxf(acc[7], 0.f));
        *(uint4*)&k1f[slot * 8] = o;
    }
    __syncthreads();

    // layer 2: [32,128]@[128,256] via mfma_32x32x16_f16, both col-groups live
    const int w  = t >> 6, l = t & 63;
    const int li = l & 31, hf = l >> 5;
    floatx16 accA, accB;
#pragma unroll
    for (int r = 0; r < 16; r++) { accA[r] = 0.f; accB[r] = 0.f; }
    {
        const int cA = w * 2, cB = w * 2 + 1;
#pragma unroll
        for (int s = 0; s < 8; s++) {
            const half8 a = __builtin_bit_cast(half8,
                *(const uint4*)&k1f[(s * 64 + l) * 8]);
            const half8 bA = __builtin_bit_cast(half8,
                *(const uint4*)&w2h[(((size_t)cA * 8 + s) * 64 + l) * 8]);
            const half8 bB = __builtin_bit_cast(half8,
                *(const uint4*)&w2h[(((size_t)cB * 8 + s) * 64 + l) * 8]);
            accA = __builtin_amdgcn_mfma_f32_32x32x16_f16(a, bA, accA, 0, 0, 0);
            accB = __builtin_amdgcn_mfma_f32_32x32x16_f16(a, bB, accB, 0, 0, 0);
        }
        const float bbA = b2[cA * 32 + li];
        const float bbB = b2[cB * 32 + li];
#pragma unroll
        for (int r = 0; r < 16; r++) {
            accA[r] = fmaxf(accA[r] + bbA, 0.f);
            accB[r] = fmaxf(accB[r] + bbB, 0.f);
        }
    }

    // per-edge max over this wave's 64 cols (rows of C-frag are edges)
#pragma unroll
    for (int r = 0; r < 16; r++) {
        float v = fmaxf(accA[r], accB[r]);
        v = fmaxf(v, __shfl_xor(v, 1, 64));
        v = fmaxf(v, __shfl_xor(v, 2, 64));
        v = fmaxf(v, __shfl_xor(v, 4, 64));
        v = fmaxf(v, __shfl_xor(v, 8, 64));
        v = fmaxf(v, __shfl_xor(v, 16, 64));
        if (li == 0) {
            const int e = (r & 3) + 8 * (r >> 2) + 4 * hf;
            pmax_s[w][e] = v;
        }
    }
    __syncthreads();
    if (t < 32) {
        const float mx = fmaxf(fmaxf(pmax_s[0][t], pmax_s[1][t]),
                               fmaxf(pmax_s[2][t], pmax_s[3][t]));
        k2s[e0 + t] = (u16)f2h(mx / 255.f);
        invS[t] = (mx > 0.f) ? 255.f / mx : 0.f;
    }
    __syncthreads();

    // quantize from registers into u8 LDS (magic-const RNE: byte0 = rint)
    {
        const float magic = 8388608.f;   // 2^23
#pragma unroll
        for (int r = 0; r < 16; r++) {
            const int e = (r & 3) + 8 * (r >> 2) + 4 * hf;
            const float inv = invS[e];
            const u32 qA = __builtin_bit_cast(u32, fmaf(accA[r], inv, magic));
            const u32 qB = __builtin_bit_cast(u32, fmaf(accB[r], inv, magic));
            M8[e * 272 + (w * 2 + 0) * 32 + li] = (u8)qA;
            M8[e * 272 + (w * 2 + 1) * 32 + li] = (u8)qB;
        }
    }
    __syncthreads();

    // copy out: thread t -> edge el=t&31, col-chunk qq=t>>5 (32 cols)
    {
        const int el = t & 31, qq = t >> 5;
        const uint4 o0 = *(const uint4*)&M8[el * 272 + qq * 32];
        const uint4 o1 = *(const uint4*)&M8[el * 272 + qq * 32 + 16];
        u8* outp = k2base + (size_t)(e0 + el) * 256 + qq * 32;
        *(uint4*)outp        = o0;
        *(uint4*)(outp + 16) = o1;
    }
}

// ---------------------------------------------------------------------------
// G = h @ W3t via MFMA. Write-bound: 164 MB fp16 per layer.
// ---------------------------------------------------------------------------
__global__ __launch_bounds__(256) void g_kernel(
    const float* __restrict__ h, const u16* __restrict__ w3g,
    u16* __restrict__ Gg)
{
    const int t = threadIdx.x, w = t >> 6, l = t & 63;
    const int li = l & 31, hf = l >> 5;
    const int n0 = blockIdx.x * 32;
    const int node = n0 + li;

    half8 a0, a1;   // A-frags: row=li(node), k = hf*8+j (+16 for kstep 1)
    if (node < NN) {
        const float* hp = &h[(size_t)node * 32 + hf * 8];
        const float4 x0 = *(const float4*)hp;
        const float4 x1 = *(const float4*)(hp + 4);
        const float4 y0 = *(const float4*)(hp + 16);
        const float4 y1 = *(const float4*)(hp + 20);
        uint4 ua, ub;
        ua.x = pkrtz2(x0.x, x0.y); ua.y = pkrtz2(x0.z, x0.w);
        ua.z = pkrtz2(x1.x, x1.y); ua.w = pkrtz2(x1.z, x1.w);
        ub.x = pkrtz2(y0.x, y0.y); ub.y = pkrtz2(y0.z, y0.w);
        ub.z = pkrtz2(y1.x, y1.y); ub.w = pkrtz2(y1.z, y1.w);
        a0 = __builtin_bit_cast(half8, ua);
        a1 = __builtin_bit_cast(half8, ub);
    } else {
        const uint4 z = make_uint4(0u, 0u, 0u, 0u);
        a0 = __builtin_bit_cast(half8, z);
        a1 = __builtin_bit_cast(half8, z);
    }

    const int pt0 = blockIdx.y * 64 + w * 16;
    const int full = (n0 + 32 <= NN) ? 1 : 0;
#pragma unroll 4
    for (int it = 0; it < 16; it++) {
        const int pt = pt0 + it;
        const uint4 b0u = *(const uint4*)&w3g[((size_t)pt * 2 + 0) * 512 + (size_t)l * 8];
        const uint4 b1u = *(const uint4*)&w3g[((size_t)pt * 2 + 1) * 512 + (size_t)l * 8];
        floatx16 acc;
#pragma unroll
        for (int r = 0; r < 16; r++) acc[r] = 0.f;
        acc = __builtin_amdgcn_mfma_f32_32x32x16_f16(
            a0, __builtin_bit_cast(half8, b0u), acc, 0, 0, 0);
        acc = __builtin_amdgcn_mfma_f32_32x32x16_f16(
            a1, __builtin_bit_cast(half8, b1u), acc, 0, 0, 0);
        if (full) {
#pragma unroll
            for (int r = 0; r < 16; r++) {
                const int nn = n0 + (r & 3) + 8 * (r >> 2) + 4 * hf;
                Gg[(size_t)nn * 8192 + pt * 32 + li] = (u16)f2h(acc[r]);
            }
        } else {
#pragma unroll
            for (int r = 0; r < 16; r++) {
                const int nn = n0 + (r & 3) + 8 * (r >> 2) + 4 * hf;
                if (nn < NN)
                    Gg[(size_t)nn * 8192 + pt * 32 + li] = (u16)f2h(acc[r]);
            }
        }
    }
}

// ---------------------------------------------------------------------------
// MFMA edge pass (round-2 structure: deep upfront prefetch). One wave64 per
// col-node n. gr[16] = the node's FULL 16 KB G row, hoisted OUT of the chunk
// loop (loop-invariant) -> loaded once per node, reused across chunks.
// kr[16] upfront per chunk keeps 8 KB/wave of k2 loads in flight.
// ---------------------------------------------------------------------------
__global__ __launch_bounds__(256, 3) void edge_kernel(
    const int* __restrict__ cstart, const int* __restrict__ elist,
    const int* __restrict__ ridx, const int* __restrict__ rpos,
    const u8* __restrict__ k2base, const u16* __restrict__ k2s,
    const u16* __restrict__ Gg, const float* __restrict__ coord,
    const u16* __restrict__ cmpk, const float* __restrict__ cm1b,
    const float* __restrict__ cm2w, const float* __restrict__ cm2b,
    const float* __restrict__ h, const float* __restrict__ b3,
    float* __restrict__ agg, float* __restrict__ dco,
    u16* __restrict__ mbuf, u16* __restrict__ webuf, int mode)
{
    const int t    = threadIdx.x;
    const int w    = t >> 6;
    const int l    = t & 63;
    const int li   = l & 31;
    const int half = l >> 5;

    __shared__ __align__(16) float Mlds_all[4][32 * 34];
    __shared__ int   idxS_all[4][32];
    __shared__ float seS_all[4][32];
    float* Mlds = Mlds_all[w];
    int*   idxS = idxS_all[w];
    float* seS  = seS_all[w];

    const int n = blockIdx.x * 4 + w;
    if (n >= NN) return;
    const int s0  = cstart[n];
    const int deg = cstart[n + 1] - s0;
    if (deg == 0) return;

    half8 cmb[2];
    cmb[0] = __builtin_bit_cast(half8, *(const uint4*)&cmpk[(size_t)(0 * 64 + l) * 8]);
    cmb[1] = __builtin_bit_cast(half8, *(const uint4*)&cmpk[(size_t)(1 * 64 + l) * 8]);
    half8 onesb;
#pragma unroll
    for (int j = 0; j < 8; j++) onesb[j] = (_Float16)1.0f;
    const float cm1bq = cm1b[li];
    const float cm2q  = cm2w[li];
    const float cm2b0 = cm2b[0];
    // fused bvec: bv = sum_j b3[li*32+j] * h[n][j]
    float bv = 0.f;
    {
        const float* hn = &h[(size_t)n * 32];
        const float* bp = &b3[(size_t)li * 32];
#pragma unroll
        for (int c2 = 0; c2 < 8; c2++) {
            const float4 hv = *(const float4*)&hn[c2 * 4];
            const float4 bq = *(const float4*)&bp[c2 * 4];
            bv += hv.x * bq.x + hv.y * bq.y + hv.z * bq.z + hv.w * bq.w;
        }
    }
    const float con   = (mode == 0 && li < 3) ? coord[(size_t)n * 3 + li] : 0.f;
    const u16* Gn = Gg + (size_t)n * 8192;

    // hoisted: full G row for this node (16 KB/wave, 64 VGPR), loaded once
    uint4 gr[16];
    {
        const u16* grp = Gn + l * 8;
#pragma unroll
        for (int s = 0; s < 16; s++)
            gr[s] = *(const uint4*)(grp + s * 512);
    }

    for (int base = 0; base < deg; base += 32) {
        const int mye   = base + li;
        const int valid = (mye < deg) ? 1 : 0;
        const int eid   = valid ? elist[s0 + mye] : 0;
        const float se  = valid ? h2f(k2s[eid]) : 0.f;
        if (l < 32) { idxS[l] = valid ? (mode ? rpos[eid] : ridx[eid]) : 0; seS[l] = se; }

        const u8* k2row = k2base + (size_t)eid * 256 + half * 8;
        uint2 kr[16];
#pragma unroll
        for (int s = 0; s < 16; s++) kr[s] = *(const uint2*)(k2row + s * 16);

        floatx16 acc;
#pragma unroll
        for (int r = 0; r < 16; r++) acc[r] = 0.f;
#pragma unroll
        for (int s = 0; s < 16; s++) {
            uint4 au;
            au.x = dq2(kr[s].x, 0x00050004u);
            au.y = dq2(kr[s].x, 0x00070006u);
            au.z = dq2(kr[s].y, 0x00050004u);
            au.w = dq2(kr[s].y, 0x00070006u);
            acc = __builtin_amdgcn_mfma_f32_32x32x16_f16(
                __builtin_bit_cast(half8, au),
                __builtin_bit_cast(half8, gr[s]), acc, 0, 0, 0);
        }
        // per-edge scale commutes with MFMA row-wise: m = se_e * dot + bv
#pragma unroll
        for (int r = 0; r < 16; r++) {
            const int e = (r & 3) + 8 * (r >> 2) + 4 * half;
            acc[r] = acc[r] * seS[e] + bv;
        }

#pragma unroll
        for (int r = 0; r < 16; r++) {
            const int e = (r & 3) + 8 * (r >> 2) + 4 * half;
            Mlds[e * 34 + li] = acc[r];
        }
        if (mode == 0) {
#pragma unroll
            for (int r = 0; r < 16; r++) {
                const int e = (r & 3) + 8 * (r >> 2) + 4 * half;
                if (base + e < deg)
                    atomicAdd(&agg[(size_t)idxS[e] * 32 + li], acc[r]);
            }
        } else {
#pragma unroll
            for (int r = 0; r < 16; r++) {
                const int e = (r & 3) + 8 * (r >> 2) + 4 * half;
                if (base + e < deg)
                    mbuf[(size_t)idxS[e] * 32 + li] =
                        __builtin_bit_cast(u16, (_Float16)acc[r]);
            }
        }
        asm volatile("s_waitcnt lgkmcnt(0)" ::: "memory");

        floatx16 acc2;
#pragma unroll
        for (int r = 0; r < 16; r++) acc2[r] = cm1bq;
#pragma unroll
        for (int s2 = 0; s2 < 2; s2++) {
            const float* mp = &Mlds[li * 34 + s2 * 16 + half * 8];
            const float2 m0 = *(const float2*)mp;
            const float2 m1 = *(const float2*)(mp + 2);
            const float2 m2 = *(const float2*)(mp + 4);
            const float2 m3 = *(const float2*)(mp + 6);
            uint4 au;
            au.x = pkrtz2(m0.x, m0.y);
            au.y = pkrtz2(m1.x, m1.y);
            au.z = pkrtz2(m2.x, m2.y);
            au.w = pkrtz2(m3.x, m3.y);
            acc2 = __builtin_amdgcn_mfma_f32_32x32x16_f16(
                __builtin_bit_cast(half8, au), cmb[s2], acc2, 0, 0, 0);
        }

#pragma unroll
        for (int r = 0; r < 16; r++) {
            const int e = (r & 3) + 8 * (r >> 2) + 4 * half;
            Mlds[e * 34 + li] = fmaxf(acc2[r], 0.f) * cm2q;
        }
        asm volatile("s_waitcnt lgkmcnt(0)" ::: "memory");
        floatx16 acc3;
#pragma unroll
        for (int r = 0; r < 16; r++) acc3[r] = cm2b0;
#pragma unroll
        for (int s2 = 0; s2 < 2; s2++) {
            const float* mp = &Mlds[li * 34 + s2 * 16 + half * 8];
            const float2 m0 = *(const float2*)mp;
            const float2 m1 = *(const float2*)(mp + 2);
            const float2 m2 = *(const float2*)(mp + 4);
            const float2 m3 = *(const float2*)(mp + 6);
            uint4 au;
            au.x = pkrtz2(m0.x, m0.y);
            au.y = pkrtz2(m1.x, m1.y);
            au.z = pkrtz2(m2.x, m2.y);
            au.w = pkrtz2(m3.x, m3.y);
            acc3 = __builtin_amdgcn_mfma_f32_32x32x16_f16(
                __builtin_bit_cast(half8, au), onesb, acc3, 0, 0, 0);
        }

        if (mode == 0) {
#pragma unroll
            for (int r = 0; r < 16; r++) {
                const int e = (r & 3) + 8 * (r >> 2) + 4 * half;
                if (base + e < deg && li < 3) {
                    const int rr = idxS[e];
                    const float d = coord[(size_t)rr * 3 + li] - con;
                    atomicAdd(&dco[(size_t)rr * 3 + li], d * acc3[r]);
                }
            }
        } else {
#pragma unroll
            for (int r = 0; r < 16; r++) {
                const int e = (r & 3) + 8 * (r >> 2) + 4 * half;
                if (base + e < deg && li == 0)
                    webuf[idxS[e]] = __builtin_bit_cast(u16, (_Float16)acc3[r]);
            }
        }
    }
}

// ---------------------------------------------------------------------------
__global__ __launch_bounds__(256) void node_update_kernel(
    float* __restrict__ h, float* __restrict__ agg,
    float* __restrict__ coord, float* __restrict__ dco,
    const float* __restrict__ invc)
{
    int idx = blockIdx.x * 256 + threadIdx.x;
    if (idx < NN * 32) {
        int v = idx >> 5;
        h[idx] = fmaxf(h[idx] + agg[idx] * invc[v], 0.f);
        agg[idx] = 0.f;
    }
    if (idx < NN * 3) {
        coord[idx] += dco[idx] * invc[idx / 3];
        dco[idx] = 0.f;
    }
}

// ---------------------------------------------------------------------------
__global__ __launch_bounds__(256) void node_update2_kernel(
    float* __restrict__ h, const float* __restrict__ coordCur,
    float* __restrict__ coordNew, const u16* __restrict__ mbuf,
    const u16* __restrict__ webuf, const int* __restrict__ rcol,
    const int* __restrict__ rstart, const float* __restrict__ invc)
{
    const int t = threadIdx.x, w = t >> 6, l = t & 63;
    const int li = l & 31, half = l >> 5;
    const int v = blockIdx.x * 4 + w;
    if (v >= NN) return;
    const int s0 = rstart[v], s1 = rstart[v + 1];
    const float iv = invc[v];

    float acc = 0.f;
    for (int s = s0 + half; s < s1; s += 2)
        acc += h2f(mbuf[(size_t)s * 32 + li]);
    acc += __shfl_xor(acc, 32, 64);
    if (half == 0)
        h[(size_t)v * 32 + li] = fmaxf(h[(size_t)v * 32 + li] + acc * iv, 0.f);

    const float c0 = coordCur[(size_t)v * 3 + 0];
    const float c1 = coordCur[(size_t)v * 3 + 1];
    const float c2 = coordCur[(size_t)v * 3 + 2];
    float p0 = 0.f, p1 = 0.f, p2 = 0.f;
    for (int s = s0 + l; s < s1; s += 64) {
        const float we = h2f(webuf[s]);
        const int col = rcol[s];
        p0 += (c0 - coordCur[(size_t)col * 3 + 0]) * we;
        p1 += (c1 - coordCur[(size_t)col * 3 + 1]) * we;
        p2 += (c2 - coordCur[(size_t)col * 3 + 2]) * we;
    }
#pragma unroll
    for (int off = 32; off >= 1; off >>= 1) {
        p0 += __shfl_xor(p0, off, 64);
        p1 += __shfl_xor(p1, off, 64);
        p2 += __shfl_xor(p2, off, 64);
    }
    if (l == 0) {
        coordNew[(size_t)v * 3 + 0] = c0 + p0 * iv;
        coordNew[(size_t)v * 3 + 1] = c1 + p1 * iv;
        coordNew[(size_t)v * 3 + 2] = c2 + p2 * iv;
    }
}

// ---------------------------------------------------------------------------
__global__ __launch_bounds__(256) void final_kernel(
    const float* __restrict__ h, const float* __restrict__ coord,
    const float* __restrict__ wa, const float* __restrict__ ba,
    const float* __restrict__ wb, const float* __restrict__ bb,
    float* __restrict__ out)
{
    const int lane = threadIdx.x & 63;
    const int v = blockIdx.x * 4 + (threadIdx.x >> 6);
    if (v >= NN) return;
    const float hreg = (lane < 32) ? h[(size_t)v * 32 + lane] : 0.f;
    float acc = ba[lane];
#pragma unroll
    for (int f = 0; f < 32; f++) acc += __shfl(hreg, f, 64) * wa[f * 64 + lane];
    float part = fmaxf(acc, 0.f) * wb[lane];
#pragma unroll
    for (int off = 32; off >= 1; off >>= 1) part += __shfl_xor(part, off, 64);
    if (lane == 0) out[v] = part + bb[0];
    if (lane < 3) out[NN + (size_t)v * 3 + lane] = coord[(size_t)v * 3 + lane];
}

// ---------------------------------------------------------------------------
extern "C" void kernel_launch(void* const* d_in, const int* in_sizes, int n_in,
                              void* d_out, int out_size, void* d_ws, size_t ws_size,
                              hipStream_t stream)
{
    const float* x    = (const float*)d_in[0];
    const int*   ei   = (const int*)d_in[1];
    const float* ea   = (const float*)d_in[2];
    const float* ci   = (const float*)d_in[3];
    const float* fc1w = (const float*)d_in[4];
    const float* fc1b = (const float*)d_in[5];
    const float* k1w  = (const float*)d_in[6];
    const float* k1b  = (const float*)d_in[7];
    const float* k2w  = (const float*)d_in[8];
    const float* k2b  = (const float*)d_in[9];
    const float* k3w  = (const float*)d_in[10];
    const float* k3b  = (const float*)d_in[11];
    const float* cm1w = (const float*)d_in[12];
    const float* cm1b = (const float*)d_in[13];
    const float* cm2w = (const float*)d_in[14];
    const float* cm2b = (const float*)d_in[15];
    const float* f2aw = (const float*)d_in[16];
    const float* f2ab = (const float*)d_in[17];
    const float* f2bw = (const float*)d_in[18];
    const float* f2bb = (const float*)d_in[19];

    size_t o_k2, o_k2s, o_G, o_h, o_coA, o_coB, o_invc, o_rc, o_cc,
           o_cs, o_rs, o_cn, o_rn, o_el, o_w2h, o_cmpk, o_w3g, o_agg, o_dco,
           o_ri, o_ci, o_rp, o_rcl, o_mb, o_wb;
#define ALGN(v) (((v) + 255) & ~(size_t)255)
    auto carve = [&](int mode) -> size_t {
        size_t o = 0;
        o_k2  = o; o += ALGN((size_t)NE * 256);
        o_k2s = o; o += ALGN((size_t)NE * 2);          // fp16
        o_G   = o; o += ALGN((size_t)NN * 8192 * 2);
        o_h   = o; o += ALGN((size_t)NN * 32 * 4);
        o_coA = o; o += ALGN((size_t)NN * 3 * 4);
        o_invc= o; o += ALGN((size_t)NN * 4);
        o_rc  = o; o += ALGN((size_t)NN * 4);
        o_cc  = o; o += ALGN((size_t)NN * 4);
        o_cs  = o; o += ALGN((size_t)(NN + 1) * 4);
        o_cn  = o; o += ALGN((size_t)NN * 4);
        o_el  = o; o += ALGN((size_t)NE * 4);
        o_w2h = o; o += ALGN((size_t)128 * 256 * 2);
        o_cmpk= o; o += ALGN((size_t)1024 * 2);
        o_w3g = o; o += ALGN((size_t)32768 * 8 * 2);   // 512 KB W3 B-frag pack
        if (mode == 0) {
            o_agg = o; o += ALGN((size_t)NN * 32 * 4);
            o_dco = o; o += ALGN((size_t)NN * 3 * 4);
            o_ri  = o; o += ALGN((size_t)NE * 4);
            o_ci  = o; o += ALGN((size_t)NE * 4);
            o_coB = o_coA; o_rs = o_cs; o_rn = o_cn;
            o_rp = o_el; o_rcl = o_el; o_mb = o_k2; o_wb = o_k2;
        } else {
            o_coB = o; o += ALGN((size_t)NN * 3 * 4);
            o_rs  = o; o += ALGN((size_t)(NN + 1) * 4);
            o_rn  = o; o += ALGN((size_t)NN * 4);
            o_rp  = o; o += ALGN((size_t)NE * 4);
            o_rcl = o; o += ALGN((size_t)NE * 4);
            const size_t u = o;
            o_ri = u; o_ci = u + ALGN((size_t)NE * 4);
            o_mb = u; o_wb = u + ALGN((size_t)NE * 32 * 2);
            const size_t setup_sz = 2 * ALGN((size_t)NE * 4);
            const size_t layer_sz = ALGN((size_t)NE * 32 * 2) + ALGN((size_t)NE * 2);
            o += (setup_sz > layer_sz) ? setup_sz : layer_sz;
            o_agg = o_k2; o_dco = o_k2;
        }
        return o;
    };
    int mode = (ws_size >= carve(1)) ? 1 : 0;
    size_t need = carve(mode);
    if (ws_size < need) {
        sentinel_kernel<<<(NN * 4 + 255) / 256, 256, 0, stream>>>((float*)d_out, NN * 4, 1.0e6f);
        return;
    }

    char* wsb = (char*)d_ws;
    u8*    k2g   = (u8*)(wsb + o_k2);
    u16*   k2s   = (u16*)(wsb + o_k2s);
    u16*   Gg    = (u16*)(wsb + o_G);
    float* h     = (float*)(wsb + o_h);
    float* coA   = (float*)(wsb + o_coA);
    float* coB   = (float*)(wsb + o_coB);
    float* invc  = (float*)(wsb + o_invc);
    int*   rowcnt= (int*)(wsb + o_rc);
    int*   colcnt= (int*)(wsb + o_cc);
    int*   cstart= (int*)(wsb + o_cs);
    int*   rstart= (int*)(wsb + o_rs);
    int*   cnext = (int*)(wsb + o_cn);
    int*   rnext = (int*)(wsb + o_rn);
    int*   elist = (int*)(wsb + o_el);
    u16*   w2h   = (u16*)(wsb + o_w2h);
    u16*   cmpk  = (u16*)(wsb + o_cmpk);
    u16*   w3g   = (u16*)(wsb + o_w3g);
    float* agg   = (float*)(wsb + o_agg);
    float* dco   = (float*)(wsb + o_dco);
    int*   ridx  = (int*)(wsb + o_ri);
    int*   cidx  = (int*)(wsb + o_ci);
    int*   rpos  = (int*)(wsb + o_rp);
    int*   rcol  = (int*)(wsb + o_rcl);
    u16*   mbuf  = (u16*)(wsb + o_mb);
    u16*   webuf = (u16*)(wsb + o_wb);

    hipMemsetAsync(rowcnt, 0, (size_t)NN * 4, stream);
    hipMemsetAsync(colcnt, 0, (size_t)NN * 4, stream);
    if (mode == 0) {
        hipMemsetAsync(agg, 0, (size_t)NN * 32 * 4, stream);
        hipMemsetAsync(dco, 0, (size_t)NN * 3 * 4, stream);
    }

    detect_idx_kernel<<<1, 256, 0, stream>>>(ei, cnext);
    convert_idx_kernel<<<(2 * NE + 255) / 256, 256, 0, stream>>>(ei, cnext, ridx, cidx);
    init_nodes_kernel<<<(NN * 32 + 255) / 256, 256, 0, stream>>>(x, fc1w, fc1b, ci, h, coA);
    count_kernel<<<(NE + 255) / 256, 256, 0, stream>>>(ridx, cidx, rowcnt, colcnt);
    scan_kernel<<<1, 256, 0, stream>>>(colcnt, rowcnt, cstart, cnext, rstart, rnext,
                                       invc, mode);
    scatter_kernel<<<(NE + 255) / 256, 256, 0, stream>>>(cidx, ridx, cnext, rnext,
                                                         elist, rpos, rcol, mode);
    w2pack_kernel<<<16, 256, 0, stream>>>(k2w, w2h);
    cm1pack_kernel<<<1, 128, 0, stream>>>(cm1w, cmpk);
    w3pack_kernel<<<128, 256, 0, stream>>>(k3w, w3g);
    mlp_k2_kernel<<<NE / 32, 256, 0, stream>>>(ea, k1w, k1b, w2h, k2b, k2g, k2s);

    float* coCur = coA;
    float* coAlt = coB;
    const dim3 ggrid((NN + 31) / 32, 4);
    for (int l = 0; l < DEPTH; l++) {
        g_kernel<<<ggrid, 256, 0, stream>>>(h, w3g, Gg);
        edge_kernel<<<(NN + 3) / 4, 256, 0, stream>>>(cstart, elist, ridx, rpos,
                                                      k2g, k2s, Gg, coCur, cmpk,
                                                      cm1b, cm2w, cm2b, h, k3b,
                                                      agg, dco, mbuf, webuf, mode);
        if (mode == 1) {
            node_update2_kernel<<<(NN + 3) / 4, 256, 0, stream>>>(
                h, coCur, coAlt, mbuf, webuf, rcol, rstart, invc);
            float* tmp = coCur; coCur = coAlt; coAlt = tmp;
        } else {
            node_update_kernel<<<(NN * 32 + 255) / 256, 256, 0, stream>>>(
                h, agg, coCur, dco, invc);
        }
    }
    final_kernel<<<(NN + 3) / 4, 256, 0, stream>>>(h, coCur, f2aw, f2ab, f2bw, f2bb,
                                                   (float*)d_out);
}